// Round 13
// baseline (189.659 us; speedup 1.0000x reference)
//
#include <hip/hip_runtime.h>

// Problem constants.
#define B_SZ 16384
#define C_SZ 4096
#define D_SZ 512

// int8 quantization scale: x, codes ~ N(0,1); ±127/22.7 = ±5.59 covers the
// max of 8.4M normal samples (max |x| ~ 5.3); clamp catches the ~1e-8 tail.
#define QSCALE 22.7f
#define INV_S2 (1.0f / (QSCALE * QSCALE))
// Re-rank threshold in "dist units" (raw_l2/2). i8 quant err per element
// std = (1/22.7)/sqrt(12) = 0.0127 -> dot err std = sqrt(512*2)*0.0127 =
// 0.41; pairwise-difference std 0.57; EPS=6 is >10 sigma of capture failure
// over all 6.7e7 (row,code) pairs. Expected candidates/row ~ 3 -> exact
// fp32 re-rank stays cheap.
#define EPS 6.0f
// Bias making dist' = BIAS + 0.5*csq - dot strictly positive (needs
// BIAS > 0.5*xsq; 0.5*csq ~ 256+-45, |dot| <~ 110).
#define DBIAS 1024.0f

typedef __attribute__((ext_vector_type(4))) int intx4;      // i8 MFMA A/B/acc

// ---- helpers ---------------------------------------------------------------
__device__ inline unsigned q4(const float4 v) {
    int a = (int)rintf(v.x * QSCALE); a = max(-127, min(127, a));
    int b = (int)rintf(v.y * QSCALE); b = max(-127, min(127, b));
    int c = (int)rintf(v.z * QSCALE); c = max(-127, min(127, c));
    int d = (int)rintf(v.w * QSCALE); d = max(-127, min(127, d));
    return ((unsigned)(a & 255)) | ((unsigned)(b & 255) << 8) |
           ((unsigned)(c & 255) << 16) | ((unsigned)(d & 255) << 24);
}
__device__ inline void gload16(const void* g, void* l) {
    // async global->LDS, 16B/lane; LDS dest = wave-uniform base + lane*16
    __builtin_amdgcn_global_load_lds(
        (const __attribute__((address_space(1))) void*)g,
        (__attribute__((address_space(3))) void*)l, 16, 0, 0);
}

// Clobber-free waits (R3-proven formulation).
#define SCHEDB()  __builtin_amdgcn_sched_barrier(0)
#define VM0()     do { SCHEDB(); asm volatile("s_waitcnt vmcnt(0)"); SCHEDB(); } while (0)

// DPP row_ror:N within each 16-lane row -- VALU-pipe lane rotate.
#define ROR16(v, N) \
    ((unsigned)__builtin_amdgcn_update_dpp(0, (int)(v), 0x120 + (N), 0xF, 0xF, true))

// ---------------------------------------------------------------------------
// Prep (fused): x -> i8 plane; codes -> i8 plane + c_sq (exact fp32).
// Blocks [0, 8192): x elements. Blocks [8192, 9216): one wave per code row.
// ---------------------------------------------------------------------------
__global__ __launch_bounds__(256) void convert_kernel(const float* __restrict__ x,
                                                      const float* __restrict__ codes,
                                                      unsigned* __restrict__ xq,
                                                      unsigned* __restrict__ cq,
                                                      float* __restrict__ csq) {
    const int XB = (B_SZ * D_SZ) / 4 / 256;   // 8192
    if (blockIdx.x < XB) {
        const int tid = blockIdx.x * 256 + threadIdx.x;
        const float4 v = ((const float4*)x)[tid];
        xq[tid] = q4(v);
    } else {
        const int t = threadIdx.x;
        const int wave = t >> 6;
        const int lane = t & 63;
        const int code = (blockIdx.x - XB) * 4 + wave;
        const float4* cp = (const float4*)(codes + (size_t)code * D_SZ);
        float s = 0.0f;
        #pragma unroll
        for (int u = 0; u < 2; ++u) {
            const float4 v = cp[lane + 64 * u];
            cq[(size_t)code * (D_SZ / 4) + lane + 64 * u] = q4(v);
            s = fmaf(v.x, v.x, s); s = fmaf(v.y, v.y, s);
            s = fmaf(v.z, v.z, s); s = fmaf(v.w, v.w, s);
        }
        #pragma unroll
        for (int off = 32; off; off >>= 1) s += __shfl_down(s, off, 64);
        if (lane == 0) csq[code] = s;
    }
}

// ---------------------------------------------------------------------------
// Main: i8 MFMA GEMM (mfma_i32_16x16x64_i8). R13: BARRIER-FREE K-loop.
// Block = 512 rows x 256 cols. B panel (256x512 = 128 KB) staged ONCE into
// 4 persistent LDS kt slots (never overwritten); A fragments are loaded
// DIRECTLY from global xq into registers -- no A LDS, no per-phase
// barriers, no lgkm/vmcnt waits in the loop. The kernel has exactly ONE
// barrier (after the B-panel stage + vmcnt(0) drain).
// Rationale (R4-R12 evidence): the 60us plateau held across 5 structural
// variants while no pipe was saturated (MfmaUtil 22, VALU 43, HBM 9%,
// conflicts 0); the shared cost is the barrier-synchronized phase loop
// (2 x 8-wave rendezvous + full drains x 16 phases, ~3k cyc/phase of
// non-work). Removing sync lets the compiler software-pipeline the whole
// K loop and waves free-run.
// A-load coalescing: one b128 wave-load = 16 rows x 64 B fully-utilized
// segments (4 lanes per 64 B line) = the coalescing minimum for this
// access; all L2/L3-hit (xq = 8 MB, read by 16 col-blocks).
// A bytes and accumulation order are IDENTICAL to R11/R12 -> table bits
// identical -> EPS analysis unchanged. LDS = 128 KiB, 1 block/CU,
// grid 16x32 = 2 rounds.
// ---------------------------------------------------------------------------
__global__ __launch_bounds__(512, 1) void gemm_argmin_kernel(
        const unsigned char* __restrict__ xq,
        const unsigned char* __restrict__ cq,
        const float* __restrict__ csq,
        uint2* __restrict__ table) {
    __shared__ unsigned char sB[4][256][128];   // 128 KB: persistent B panel

    const int t = threadIdx.x;
    const int wave = t >> 6;     // 0..7
    const int lane = t & 63;
    const int quad = lane >> 4;
    const int l15 = lane & 15;
    const int wm = wave >> 2;    // 0..1 -> 64-row half of the 128-row tile
    const int wn = wave & 3;     // 0..3 -> 64-col quarter

    const int rowbase0 = blockIdx.y * 512;  // 4 row-tiles of 128
    const int colbase = blockIdx.x * 256;   // code cols

    // B staging geometry: one gload16 = 8 rows x 128 B, linear LDS dest,
    // pre-swizzled global source (16B chunk' = chunk ^ (row&7)).
    const int lrow = lane >> 3;                   // 0..7 within 8-row group
    const int lchunk = (lane & 7) ^ lrow;         // swizzled 16B-chunk source
    const unsigned char* gB0 = cq + (size_t)(colbase + wave * 32 + lrow) * D_SZ + lchunk * 16;

    // A direct-load base: this lane's row strip (NO swizzle -- registers,
    // not LDS banks). Per (rt,kt,ks,i): + (rt*128 + i*16)*512 + kt*128 +
    // ks*64. quad picks the 16B chunk within the 64B (ks) block.
    const unsigned char* gA0 = xq + (size_t)(rowbase0 + wm * 64 + l15) * D_SZ + quad * 16;

    // epilogue csq terms, loaded up front (L2-resident)
    float cs2[4];
    #pragma unroll
    for (int j = 0; j < 4; ++j)
        cs2[j] = fmaf(0.5f, csq[colbase + wn * 64 + j * 16 + l15], DBIAS);

#define STAGE_B(kt) do { \
        const unsigned char* _g = gB0 + (kt) * 128; \
        _Pragma("unroll") for (int u = 0; u < 4; ++u) \
            gload16(_g + (size_t)(u * 8) * D_SZ, &sB[kt][wave * 32 + u * 8][0]); \
    } while (0)
#define MERGE_STEP(N) do { \
        const unsigned ok1 = ROR16(k1, N); \
        const unsigned ok2 = ROR16(k2, N); \
        const unsigned hi = max(k1, ok1); \
        const unsigned w2 = (k1 < ok1) ? k2 : ok2; \
        k1 = min(k1, ok1); \
        k2 = min(hi, w2); \
    } while (0)

    // ---- prologue: stage ENTIRE B panel once; one drain + one barrier.
    STAGE_B(0); STAGE_B(1); STAGE_B(2); STAGE_B(3);
    VM0();
    __syncthreads();   // the ONLY barrier in this kernel

    const int hb = blockIdx.x * 4 + wn;   // 64-col group index, 0..63

    for (int rt = 0; rt < 4; ++rt) {      // runtime loop (small body)
        intx4 acc[4][4];
        #pragma unroll
        for (int i = 0; i < 4; ++i)
            #pragma unroll
            for (int j = 0; j < 4; ++j) acc[i][j] = (intx4)0;

        const unsigned char* gArt = gA0 + (size_t)rt * 128 * D_SZ;

        #pragma unroll
        for (int kt = 0; kt < 4; ++kt) {
            #pragma unroll
            for (int ks = 0; ks < 2; ++ks) {
                // A fragments direct from global (L2-hot), no sync needed
                intx4 a[4];
                #pragma unroll
                for (int i = 0; i < 4; ++i)
                    a[i] = *(const intx4*)(gArt + (size_t)(i * 16) * D_SZ + kt * 128 + ks * 64);
                // B fragments from persistent LDS (swizzled read)
                const int cc = (((ks * 4 + quad) ^ (l15 & 7))) * 16;
                intx4 b[4];
                #pragma unroll
                for (int j = 0; j < 4; ++j)
                    b[j] = *(const intx4*)&sB[kt][wn * 64 + j * 16 + l15][cc];
                #pragma unroll
                for (int i = 0; i < 4; ++i)
                    #pragma unroll
                    for (int j = 0; j < 4; ++j)
                        acc[i][j] = __builtin_amdgcn_mfma_i32_16x16x64_i8(a[i], b[j], acc[i][j], 0, 0, 0);
            }
        }

        // ---- epilogue for this 128-row tile (registers + global only)
        #pragma unroll
        for (int i = 0; i < 4; ++i) {
            #pragma unroll
            for (int r = 0; r < 4; ++r) {
                unsigned k[4];
                #pragma unroll
                for (int j = 0; j < 4; ++j) {
                    const float d = fmaf(-(float)acc[i][j][r], INV_S2, cs2[j]);   // > 0
                    k[j] = (__float_as_uint(d) & 0xFFFFFFC0u) | (unsigned)(j * 16 + l15);
                }
                const unsigned lo1 = min(k[0], k[1]), hi1 = max(k[0], k[1]);
                const unsigned lo2 = min(k[2], k[3]), hi2 = max(k[2], k[3]);
                unsigned k1 = min(lo1, lo2);
                unsigned k2 = min(max(lo1, lo2), min(hi1, hi2));
                MERGE_STEP(8); MERGE_STEP(4); MERGE_STEP(2); MERGE_STEP(1);
                if (l15 == 0) {
                    const int grow = rowbase0 + rt * 128 + wm * 64 + i * 16 + quad * 4 + r;
                    table[(size_t)grow * 64 + hb] = make_uint2(k1, k2);
                }
            }
        }
    }
#undef STAGE_B
#undef MERGE_STEP
}

// ---------------------------------------------------------------------------
// Re-rank + gather + loss partials -- the R4/R12 tail (fastest measured).
// FOUR rows per wave. Keys are positive-float bits; col = 64*lane+(key&63).
// Exact fp32 re-rank within EPS -> indices bit-exact.
// ---------------------------------------------------------------------------
__global__ __launch_bounds__(256) void rerank_gather_loss_kernel(
        const float* __restrict__ x,
        const float* __restrict__ codes,
        const float* __restrict__ csq,
        const uint2* __restrict__ table,
        float* __restrict__ outq,
        float* __restrict__ out_idx_f,
        float* __restrict__ partials) {
    __shared__ float red[4];
    const int t = threadIdx.x;
    const int wave = t >> 6;
    const int lane = t & 63;
    const int row0 = (blockIdx.x * 4 + wave) * 4;   // 4 consecutive rows

    // ---- batched independent loads: 4 table entries + 4 x rows
    uint2 e[4];
    float4 xv[4][2];
    #pragma unroll
    for (int r = 0; r < 4; ++r) {
        e[r] = table[(size_t)(row0 + r) * 64 + lane];
        const float4* xp = (const float4*)(x + (size_t)(row0 + r) * D_SZ);
        xv[r][0] = xp[lane];
        xv[r][1] = xp[lane + 64];
    }

    // ---- resolve argmin per row
    int fin[4];
    #pragma unroll
    for (int r = 0; r < 4; ++r) {
        const unsigned k1 = e[r].x, k2 = e[r].y;
        unsigned mk = k1;
        #pragma unroll
        for (int off = 32; off; off >>= 1)
            mk = min(mk, (unsigned)__shfl_xor((int)mk, off, 64));

        const float thr = __uint_as_float(mk & 0xFFFFFFC0u) + EPS;
        const float v1 = __uint_as_float(k1 & 0xFFFFFFC0u);
        const float v2 = __uint_as_float(k2 & 0xFFFFFFC0u);
        const unsigned long long b1 = __ballot(v1 <= thr);
        const unsigned long long b2 = __ballot(v2 <= thr);

        const unsigned long long bm = __ballot(k1 == mk);
        fin[r] = (__ffsll(bm) - 1) * 64 + (int)(mk & 63u);

        if (__popcll(b1) + __popcll(b2) > 1) {       // exact fp32 re-rank
            const int c1 = lane * 64 + (int)(k1 & 63u);
            const int c2 = lane * 64 + (int)(k2 & 63u);
            float bv = 3.4e38f; int bi = 0x7FFFFFFF;
            #pragma unroll
            for (int pass = 0; pass < 2; ++pass) {
                unsigned long long bb = pass ? b2 : b1;
                const int myc = pass ? c2 : c1;
                while (bb) {
                    const int src = __ffsll((unsigned long long)bb) - 1;
                    bb &= bb - 1;
                    const int ci = __shfl(myc, src, 64);
                    const float4* cp = (const float4*)(codes + (size_t)ci * D_SZ);
                    const float4 c0 = cp[lane];
                    const float4 c1v = cp[lane + 64];
                    float s = 0.0f;
                    s = fmaf(xv[r][0].x, c0.x, s);  s = fmaf(xv[r][0].y, c0.y, s);
                    s = fmaf(xv[r][0].z, c0.z, s);  s = fmaf(xv[r][0].w, c0.w, s);
                    s = fmaf(xv[r][1].x, c1v.x, s); s = fmaf(xv[r][1].y, c1v.y, s);
                    s = fmaf(xv[r][1].z, c1v.z, s); s = fmaf(xv[r][1].w, c1v.w, s);
                    #pragma unroll
                    for (int off = 32; off; off >>= 1) s += __shfl_xor(s, off, 64);
                    const float d = fmaf(0.5f, csq[ci], -s);   // exact fp32
                    if (d < bv || (d == bv && ci < bi)) { bv = d; bi = ci; }
                }
            }
            fin[r] = bi;
        }
    }

    // ---- batched independent gathers
    float4 qv[4][2];
    #pragma unroll
    for (int r = 0; r < 4; ++r) {
        const float4* qp = (const float4*)(codes + (size_t)fin[r] * D_SZ);
        qv[r][0] = qp[lane];
        qv[r][1] = qp[lane + 64];
    }

    // ---- writes + loss partial
    float s = 0.0f;
    #pragma unroll
    for (int r = 0; r < 4; ++r) {
        float4* op = (float4*)(outq + (size_t)(row0 + r) * D_SZ);
        op[lane] = qv[r][0];
        op[lane + 64] = qv[r][1];
        const float d0 = xv[r][0].x - qv[r][0].x, d1 = xv[r][0].y - qv[r][0].y;
        const float d2 = xv[r][0].z - qv[r][0].z, d3 = xv[r][0].w - qv[r][0].w;
        const float d4 = xv[r][1].x - qv[r][1].x, d5 = xv[r][1].y - qv[r][1].y;
        const float d6 = xv[r][1].z - qv[r][1].z, d7 = xv[r][1].w - qv[r][1].w;
        s += d0 * d0 + d1 * d1 + d2 * d2 + d3 * d3 + d4 * d4 + d5 * d5 + d6 * d6 + d7 * d7;
        if (lane == 0) out_idx_f[row0 + r] = (float)fin[r];
    }
    #pragma unroll
    for (int off = 32; off; off >>= 1) s += __shfl_down(s, off, 64);
    if (lane == 0) red[wave] = s;
    __syncthreads();
    if (t == 0) partials[blockIdx.x] = red[0] + red[1] + red[2] + red[3];
}

// ---------------------------------------------------------------------------
// Loss: sum 1024 block partials -> loss_slot. One block.
// ---------------------------------------------------------------------------
__global__ __launch_bounds__(256) void loss_reduce_kernel(const float* __restrict__ partials,
                                                          float* __restrict__ loss_slot) {
    __shared__ float red[4];
    const int t = threadIdx.x;
    const int wave = t >> 6;
    const int lane = t & 63;
    float s = 0.0f;
    #pragma unroll
    for (int i = 0; i < (B_SZ / 16) / 256; ++i) s += partials[i * 256 + t];
    #pragma unroll
    for (int off = 32; off; off >>= 1) s += __shfl_down(s, off, 64);
    if (lane == 0) red[wave] = s;
    __syncthreads();
    if (t == 0)
        *loss_slot = (red[0] + red[1] + red[2] + red[3]) * (1.25f / (float)B_SZ);
}

// ---------------------------------------------------------------------------
extern "C" void kernel_launch(void* const* d_in, const int* in_sizes, int n_in,
                              void* d_out, int out_size, void* d_ws, size_t ws_size,
                              hipStream_t stream) {
    const float* x = (const float*)d_in[0];
    const float* codes = (const float*)d_in[1];  // (1, C, D) contiguous

    float* outq = (float*)d_out;                       // [B*D]
    float* out_idx_f = outq + (size_t)B_SZ * D_SZ;     // [B]
    float* loss_slot = out_idx_f + B_SZ;               // [1]

    // workspace: xq 8M | cq 2M | csq 16K | table 8M (uint2) | partials 4K
    unsigned char* xq = (unsigned char*)d_ws;
    unsigned char* cq = xq + (size_t)B_SZ * D_SZ;
    float* csq = (float*)(cq + (size_t)C_SZ * D_SZ);
    uint2* table = (uint2*)(csq + C_SZ);
    float* partials = (float*)(table + (size_t)B_SZ * 64);

    const int XB = (B_SZ * D_SZ) / 4 / 256;           // 8192
    const int CB = C_SZ / 4;                          // 1024
    convert_kernel<<<XB + CB, 256, 0, stream>>>(x, codes, (unsigned*)xq, (unsigned*)cq, csq);
    gemm_argmin_kernel<<<dim3(C_SZ / 256, B_SZ / 512), 512, 0, stream>>>(xq, cq, csq, table);
    rerank_gather_loss_kernel<<<B_SZ / 16, 256, 0, stream>>>(x, codes, csq, table, outq, out_idx_f, partials);
    loss_reduce_kernel<<<1, 256, 0, stream>>>(partials, loss_slot);
}

// Round 14
// 164.926 us; speedup vs baseline: 1.1500x; 1.1500x over previous
//
#include <hip/hip_runtime.h>

// Problem constants.
#define B_SZ 16384
#define C_SZ 4096
#define D_SZ 512

// int8 quantization scale: x, codes ~ N(0,1); ±127/22.7 = ±5.59 covers the
// max of 8.4M normal samples (max |x| ~ 5.3); clamp catches the ~1e-8 tail.
#define QSCALE 22.7f
#define INV_S2 (1.0f / (QSCALE * QSCALE))
// Re-rank threshold in "dist units" (raw_l2/2). i8 quant err per element
// std = (1/22.7)/sqrt(12) = 0.0127 -> dot err std = sqrt(512*2)*0.0127 =
// 0.41; pairwise-difference std 0.57; EPS=6 is >10 sigma of capture failure
// over all 6.7e7 (row,code) pairs. Expected candidates/row ~ 3 -> exact
// fp32 re-rank stays cheap.
#define EPS 6.0f
// Bias making dist' = BIAS + 0.5*csq - dot strictly positive (needs
// BIAS > 0.5*xsq; 0.5*csq ~ 256+-45, |dot| <~ 110).
#define DBIAS 1024.0f

typedef __attribute__((ext_vector_type(4))) int intx4;      // i8 MFMA A/B/acc

// ---- helpers ---------------------------------------------------------------
__device__ inline unsigned q4(const float4 v) {
    int a = (int)rintf(v.x * QSCALE); a = max(-127, min(127, a));
    int b = (int)rintf(v.y * QSCALE); b = max(-127, min(127, b));
    int c = (int)rintf(v.z * QSCALE); c = max(-127, min(127, c));
    int d = (int)rintf(v.w * QSCALE); d = max(-127, min(127, d));
    return ((unsigned)(a & 255)) | ((unsigned)(b & 255) << 8) |
           ((unsigned)(c & 255) << 16) | ((unsigned)(d & 255) << 24);
}
__device__ inline void gload16(const void* g, void* l) {
    // async global->LDS, 16B/lane; LDS dest = wave-uniform base + lane*16
    __builtin_amdgcn_global_load_lds(
        (const __attribute__((address_space(1))) void*)g,
        (__attribute__((address_space(3))) void*)l, 16, 0, 0);
}

// Clobber-free waits (R3-proven formulation: no "memory" clobber, pinned
// with sched_barrier so the issue-order ledger stays intact).
#define SCHEDB()  __builtin_amdgcn_sched_barrier(0)
#define VM0()     do { SCHEDB(); asm volatile("s_waitcnt vmcnt(0)"); SCHEDB(); } while (0)
#define LGKM0()   do { asm volatile("s_waitcnt lgkmcnt(0)"); SCHEDB(); } while (0)

// DPP row_ror:N within each 16-lane row -- VALU-pipe lane rotate.
#define ROR16(v, N) \
    ((unsigned)__builtin_amdgcn_update_dpp(0, (int)(v), 0x120 + (N), 0xF, 0xF, true))

// ---------------------------------------------------------------------------
// Prep (fused): x -> i8 plane; codes -> i8 plane + c_sq (exact fp32).
// Blocks [0, 8192): x elements. Blocks [8192, 9216): one wave per code row.
// ---------------------------------------------------------------------------
__global__ __launch_bounds__(256) void convert_kernel(const float* __restrict__ x,
                                                      const float* __restrict__ codes,
                                                      unsigned* __restrict__ xq,
                                                      unsigned* __restrict__ cq,
                                                      float* __restrict__ csq) {
    const int XB = (B_SZ * D_SZ) / 4 / 256;   // 8192
    if (blockIdx.x < XB) {
        const int tid = blockIdx.x * 256 + threadIdx.x;
        const float4 v = ((const float4*)x)[tid];
        xq[tid] = q4(v);
    } else {
        const int t = threadIdx.x;
        const int wave = t >> 6;
        const int lane = t & 63;
        const int code = (blockIdx.x - XB) * 4 + wave;
        const float4* cp = (const float4*)(codes + (size_t)code * D_SZ);
        float s = 0.0f;
        #pragma unroll
        for (int u = 0; u < 2; ++u) {
            const float4 v = cp[lane + 64 * u];
            cq[(size_t)code * (D_SZ / 4) + lane + 64 * u] = q4(v);
            s = fmaf(v.x, v.x, s); s = fmaf(v.y, v.y, s);
            s = fmaf(v.z, v.z, s); s = fmaf(v.w, v.w, s);
        }
        #pragma unroll
        for (int off = 32; off; off >>= 1) s += __shfl_down(s, off, 64);
        if (lane == 0) csq[code] = s;
    }
}

// ---------------------------------------------------------------------------
// Main: i8 MFMA GEMM (mfma_i32_16x16x64_i8) -- VERBATIM the R11/R12 kernel
// (best measured: 59.9-60.3us, 3 reproductions). Block = 512 rows x 256
// cols. B panel (128 KB) staged ONCE into 4 persistent kt slots; A single
// 16 KB buffer with register staging. LDS = 144 KiB, 1 block/CU, grid
// 16x32 = 2 rounds. Phase: ds_read A->regs, lgkm(0), barrier, stage next
// A (+B on rt0), MFMA from regs + B LDS, explicit vmcnt(0), barrier.
// Session verdict (R2-R13): every counter-suggested mechanism tested and
// falsified as dominant -- schedule depth (R2/R3), buffer count (R6/R7),
// stage granularity (R6), drain size/occupancy (R11), LDS pipe (R9),
// barriers (R13: removing them LOST 35us -- global-direct A puts L2
// latency on the MFMA critical path). 60us = composite latency-bound
// equilibrium at ~27.5% of i8 peak, consistent with the guide's short-K
// (K<=1024) references.
// ---------------------------------------------------------------------------
__global__ __launch_bounds__(512, 1) void gemm_argmin_kernel(
        const unsigned char* __restrict__ xq,
        const unsigned char* __restrict__ cq,
        const float* __restrict__ csq,
        uint2* __restrict__ table) {
    __shared__ unsigned char sB[4][256][128];   // 128 KB: persistent B panel
    __shared__ unsigned char sA[128][128];      // 16 KB: single A buffer

    const int t = threadIdx.x;
    const int wave = t >> 6;     // 0..7
    const int lane = t & 63;
    const int quad = lane >> 4;
    const int l15 = lane & 15;
    const int wm = wave >> 2;    // 0..1 -> 64-row half of the 128-row tile
    const int wn = wave & 3;     // 0..3 -> 64-col quarter

    const int rowbase0 = blockIdx.y * 512;  // 4 row-tiles of 128
    const int colbase = blockIdx.x * 256;   // code cols

    // staging geometry: one gload16 = 8 rows x 128 B, linear LDS dest,
    // pre-swizzled global source (16B chunk' = chunk ^ (row&7)).
    const int lrow = lane >> 3;                   // 0..7 within 8-row group
    const int lchunk = (lane & 7) ^ lrow;         // swizzled 16B-chunk source
    const unsigned char* gA0 = xq + (size_t)(rowbase0 + wave * 16 + lrow) * D_SZ + lchunk * 16;
    const unsigned char* gB0 = cq + (size_t)(colbase + wave * 32 + lrow) * D_SZ + lchunk * 16;

    // epilogue csq terms, loaded up front (L2-resident)
    float cs2[4];
    #pragma unroll
    for (int j = 0; j < 4; ++j)
        cs2[j] = fmaf(0.5f, csq[colbase + wn * 64 + j * 16 + l15], DBIAS);

#define STAGE_A(rt, kt) do { \
        const unsigned char* _g = gA0 + (size_t)(rt) * 128 * D_SZ + (kt) * 128; \
        gload16(_g,                    &sA[wave * 16][0]); \
        gload16(_g + (size_t)8 * D_SZ, &sA[wave * 16 + 8][0]); \
    } while (0)
#define STAGE_B(kt) do { \
        const unsigned char* _g = gB0 + (kt) * 128; \
        _Pragma("unroll") for (int u = 0; u < 4; ++u) \
            gload16(_g + (size_t)(u * 8) * D_SZ, &sB[kt][wave * 32 + u * 8][0]); \
    } while (0)
#define LDA_REGS() do { \
        _Pragma("unroll") for (int ks = 0; ks < 2; ++ks) { \
            const int cc = (((ks * 4 + quad) ^ (l15 & 7))) * 16; \
            _Pragma("unroll") for (int i = 0; i < 4; ++i) \
                areg[ks][i] = *(const intx4*)&sA[wm * 64 + i * 16 + l15][cc]; \
        } \
    } while (0)
#define COMPUTE_KT(kt) do { \
        _Pragma("unroll") for (int ks = 0; ks < 2; ++ks) { \
            const int cc = (((ks * 4 + quad) ^ (l15 & 7))) * 16; \
            intx4 b[4]; \
            _Pragma("unroll") for (int j = 0; j < 4; ++j) \
                b[j] = *(const intx4*)&sB[kt][wn * 64 + j * 16 + l15][cc]; \
            _Pragma("unroll") for (int i = 0; i < 4; ++i) \
                _Pragma("unroll") for (int j = 0; j < 4; ++j) \
                    acc[i][j] = __builtin_amdgcn_mfma_i32_16x16x64_i8(areg[ks][i], b[j], acc[i][j], 0, 0, 0); \
        } \
    } while (0)
#define MERGE_STEP(N) do { \
        const unsigned ok1 = ROR16(k1, N); \
        const unsigned ok2 = ROR16(k2, N); \
        const unsigned hi = max(k1, ok1); \
        const unsigned w2 = (k1 < ok1) ? k2 : ok2; \
        k1 = min(k1, ok1); \
        k2 = min(hi, w2); \
    } while (0)

    // prologue: B slot 0 + A(rt=0, kt=0); explicit drain before first read
    STAGE_B(0);
    STAGE_A(0, 0);
    VM0();
    __syncthreads();

    const int hb = blockIdx.x * 4 + wn;   // 64-col group index, 0..63

    for (int rt = 0; rt < 4; ++rt) {      // runtime loop (small body)
        intx4 acc[4][4];
        #pragma unroll
        for (int i = 0; i < 4; ++i)
            #pragma unroll
            for (int j = 0; j < 4; ++j) acc[i][j] = (intx4)0;

        #pragma unroll
        for (int kt = 0; kt < 4; ++kt) {
            intx4 areg[2][4];
            LDA_REGS();                     // [1] A -> regs
            LGKM0();                        // [2] my reads complete
            __syncthreads();                // [3] all waves' reads complete
            if (kt < 3) STAGE_A(rt, kt + 1);          // [4] overwrite is safe
            else if (rt < 3) STAGE_A(rt + 1, 0);
            if (rt == 0 && kt < 3) STAGE_B(kt + 1);
            COMPUTE_KT(kt);                 // [5] MFMA from regs + B LDS
            VM0();                          // [6] stage landed
            __syncthreads();
        }

        // ---- epilogue for this 128-row tile (registers + global only)
        #pragma unroll
        for (int i = 0; i < 4; ++i) {
            #pragma unroll
            for (int r = 0; r < 4; ++r) {
                unsigned k[4];
                #pragma unroll
                for (int j = 0; j < 4; ++j) {
                    const float d = fmaf(-(float)acc[i][j][r], INV_S2, cs2[j]);   // > 0
                    k[j] = (__float_as_uint(d) & 0xFFFFFFC0u) | (unsigned)(j * 16 + l15);
                }
                const unsigned lo1 = min(k[0], k[1]), hi1 = max(k[0], k[1]);
                const unsigned lo2 = min(k[2], k[3]), hi2 = max(k[2], k[3]);
                unsigned k1 = min(lo1, lo2);
                unsigned k2 = min(max(lo1, lo2), min(hi1, hi2));
                MERGE_STEP(8); MERGE_STEP(4); MERGE_STEP(2); MERGE_STEP(1);
                if (l15 == 0) {
                    const int grow = rowbase0 + rt * 128 + wm * 64 + i * 16 + quad * 4 + r;
                    table[(size_t)grow * 64 + hb] = make_uint2(k1, k2);
                }
            }
        }
    }
#undef STAGE_A
#undef STAGE_B
#undef LDA_REGS
#undef COMPUTE_KT
#undef MERGE_STEP
}

// ---------------------------------------------------------------------------
// Re-rank + gather + loss partials -- the R4/R12 tail (fastest measured).
// FOUR rows per wave (batched table loads + x loads, resolve, batched
// gathers). Keys are positive-float bits; col = 64*lane + (key & 63).
// Exact fp32 re-rank within EPS -> indices bit-exact.
// ---------------------------------------------------------------------------
__global__ __launch_bounds__(256) void rerank_gather_loss_kernel(
        const float* __restrict__ x,
        const float* __restrict__ codes,
        const float* __restrict__ csq,
        const uint2* __restrict__ table,
        float* __restrict__ outq,
        float* __restrict__ out_idx_f,
        float* __restrict__ partials) {
    __shared__ float red[4];
    const int t = threadIdx.x;
    const int wave = t >> 6;
    const int lane = t & 63;
    const int row0 = (blockIdx.x * 4 + wave) * 4;   // 4 consecutive rows

    // ---- batched independent loads: 4 table entries + 4 x rows
    uint2 e[4];
    float4 xv[4][2];
    #pragma unroll
    for (int r = 0; r < 4; ++r) {
        e[r] = table[(size_t)(row0 + r) * 64 + lane];
        const float4* xp = (const float4*)(x + (size_t)(row0 + r) * D_SZ);
        xv[r][0] = xp[lane];
        xv[r][1] = xp[lane + 64];
    }

    // ---- resolve argmin per row
    int fin[4];
    #pragma unroll
    for (int r = 0; r < 4; ++r) {
        const unsigned k1 = e[r].x, k2 = e[r].y;
        unsigned mk = k1;
        #pragma unroll
        for (int off = 32; off; off >>= 1)
            mk = min(mk, (unsigned)__shfl_xor((int)mk, off, 64));

        const float thr = __uint_as_float(mk & 0xFFFFFFC0u) + EPS;
        const float v1 = __uint_as_float(k1 & 0xFFFFFFC0u);
        const float v2 = __uint_as_float(k2 & 0xFFFFFFC0u);
        const unsigned long long b1 = __ballot(v1 <= thr);
        const unsigned long long b2 = __ballot(v2 <= thr);

        const unsigned long long bm = __ballot(k1 == mk);
        fin[r] = (__ffsll(bm) - 1) * 64 + (int)(mk & 63u);

        if (__popcll(b1) + __popcll(b2) > 1) {       // exact fp32 re-rank
            const int c1 = lane * 64 + (int)(k1 & 63u);
            const int c2 = lane * 64 + (int)(k2 & 63u);
            float bv = 3.4e38f; int bi = 0x7FFFFFFF;
            #pragma unroll
            for (int pass = 0; pass < 2; ++pass) {
                unsigned long long bb = pass ? b2 : b1;
                const int myc = pass ? c2 : c1;
                while (bb) {
                    const int src = __ffsll((unsigned long long)bb) - 1;
                    bb &= bb - 1;
                    const int ci = __shfl(myc, src, 64);
                    const float4* cp = (const float4*)(codes + (size_t)ci * D_SZ);
                    const float4 c0 = cp[lane];
                    const float4 c1v = cp[lane + 64];
                    float s = 0.0f;
                    s = fmaf(xv[r][0].x, c0.x, s);  s = fmaf(xv[r][0].y, c0.y, s);
                    s = fmaf(xv[r][0].z, c0.z, s);  s = fmaf(xv[r][0].w, c0.w, s);
                    s = fmaf(xv[r][1].x, c1v.x, s); s = fmaf(xv[r][1].y, c1v.y, s);
                    s = fmaf(xv[r][1].z, c1v.z, s); s = fmaf(xv[r][1].w, c1v.w, s);
                    #pragma unroll
                    for (int off = 32; off; off >>= 1) s += __shfl_xor(s, off, 64);
                    const float d = fmaf(0.5f, csq[ci], -s);   // exact fp32
                    if (d < bv || (d == bv && ci < bi)) { bv = d; bi = ci; }
                }
            }
            fin[r] = bi;
        }
    }

    // ---- batched independent gathers
    float4 qv[4][2];
    #pragma unroll
    for (int r = 0; r < 4; ++r) {
        const float4* qp = (const float4*)(codes + (size_t)fin[r] * D_SZ);
        qv[r][0] = qp[lane];
        qv[r][1] = qp[lane + 64];
    }

    // ---- writes + loss partial
    float s = 0.0f;
    #pragma unroll
    for (int r = 0; r < 4; ++r) {
        float4* op = (float4*)(outq + (size_t)(row0 + r) * D_SZ);
        op[lane] = qv[r][0];
        op[lane + 64] = qv[r][1];
        const float d0 = xv[r][0].x - qv[r][0].x, d1 = xv[r][0].y - qv[r][0].y;
        const float d2 = xv[r][0].z - qv[r][0].z, d3 = xv[r][0].w - qv[r][0].w;
        const float d4 = xv[r][1].x - qv[r][1].x, d5 = xv[r][1].y - qv[r][1].y;
        const float d6 = xv[r][1].z - qv[r][1].z, d7 = xv[r][1].w - qv[r][1].w;
        s += d0 * d0 + d1 * d1 + d2 * d2 + d3 * d3 + d4 * d4 + d5 * d5 + d6 * d6 + d7 * d7;
        if (lane == 0) out_idx_f[row0 + r] = (float)fin[r];
    }
    #pragma unroll
    for (int off = 32; off; off >>= 1) s += __shfl_down(s, off, 64);
    if (lane == 0) red[wave] = s;
    __syncthreads();
    if (t == 0) partials[blockIdx.x] = red[0] + red[1] + red[2] + red[3];
}

// ---------------------------------------------------------------------------
// Loss: sum 1024 block partials -> loss_slot. One block.
// ---------------------------------------------------------------------------
__global__ __launch_bounds__(256) void loss_reduce_kernel(const float* __restrict__ partials,
                                                          float* __restrict__ loss_slot) {
    __shared__ float red[4];
    const int t = threadIdx.x;
    const int wave = t >> 6;
    const int lane = t & 63;
    float s = 0.0f;
    #pragma unroll
    for (int i = 0; i < (B_SZ / 16) / 256; ++i) s += partials[i * 256 + t];
    #pragma unroll
    for (int off = 32; off; off >>= 1) s += __shfl_down(s, off, 64);
    if (lane == 0) red[wave] = s;
    __syncthreads();
    if (t == 0)
        *loss_slot = (red[0] + red[1] + red[2] + red[3]) * (1.25f / (float)B_SZ);
}

// ---------------------------------------------------------------------------
extern "C" void kernel_launch(void* const* d_in, const int* in_sizes, int n_in,
                              void* d_out, int out_size, void* d_ws, size_t ws_size,
                              hipStream_t stream) {
    const float* x = (const float*)d_in[0];
    const float* codes = (const float*)d_in[1];  // (1, C, D) contiguous

    float* outq = (float*)d_out;                       // [B*D]
    float* out_idx_f = outq + (size_t)B_SZ * D_SZ;     // [B]
    float* loss_slot = out_idx_f + B_SZ;               // [1]

    // workspace: xq 8M | cq 2M | csq 16K | table 8M (uint2) | partials 4K
    unsigned char* xq = (unsigned char*)d_ws;
    unsigned char* cq = xq + (size_t)B_SZ * D_SZ;
    float* csq = (float*)(cq + (size_t)C_SZ * D_SZ);
    uint2* table = (uint2*)(csq + C_SZ);
    float* partials = (float*)(table + (size_t)B_SZ * 64);

    const int XB = (B_SZ * D_SZ) / 4 / 256;           // 8192
    const int CB = C_SZ / 4;                          // 1024
    convert_kernel<<<XB + CB, 256, 0, stream>>>(x, codes, (unsigned*)xq, (unsigned*)cq, csq);
    gemm_argmin_kernel<<<dim3(C_SZ / 256, B_SZ / 512), 512, 0, stream>>>(xq, cq, csq, table);
    rerank_gather_loss_kernel<<<B_SZ / 16, 256, 0, stream>>>(x, codes, csq, table, outq, out_idx_f, partials);
    loss_reduce_kernel<<<1, 256, 0, stream>>>(partials, loss_slot);
}

// Round 15
// 161.632 us; speedup vs baseline: 1.1734x; 1.0204x over previous
//
#include <hip/hip_runtime.h>

// Problem constants.
#define B_SZ 16384
#define C_SZ 4096
#define D_SZ 512

// int8 quantization scale: x, codes ~ N(0,1); ±127/22.7 = ±5.59 covers the
// max of 8.4M normal samples (max |x| ~ 5.3); clamp catches the ~1e-8 tail.
#define QSCALE 22.7f
#define INV_S2 (1.0f / (QSCALE * QSCALE))
// Re-rank threshold in "dist units" (raw_l2/2). i8 quant err per element
// std = (1/22.7)/sqrt(12) = 0.0127 -> dot err std = sqrt(512*2)*0.0127 =
// 0.41; pairwise-difference std 0.57; EPS=6 is >10 sigma of capture failure
// over all 6.7e7 (row,code) pairs. Expected candidates/row ~ 3 -> exact
// fp32 re-rank stays cheap.
#define EPS 6.0f
// Bias making dist' = BIAS + 0.5*csq - dot strictly positive (needs
// BIAS > 0.5*xsq; 0.5*csq ~ 256+-45, |dot| <~ 110).
#define DBIAS 1024.0f

typedef __attribute__((ext_vector_type(4))) int intx4;      // i8 MFMA A/B/acc

// ---- helpers ---------------------------------------------------------------
__device__ inline unsigned q4(const float4 v) {
    int a = (int)rintf(v.x * QSCALE); a = max(-127, min(127, a));
    int b = (int)rintf(v.y * QSCALE); b = max(-127, min(127, b));
    int c = (int)rintf(v.z * QSCALE); c = max(-127, min(127, c));
    int d = (int)rintf(v.w * QSCALE); d = max(-127, min(127, d));
    return ((unsigned)(a & 255)) | ((unsigned)(b & 255) << 8) |
           ((unsigned)(c & 255) << 16) | ((unsigned)(d & 255) << 24);
}
__device__ inline void gload16(const void* g, void* l) {
    // async global->LDS, 16B/lane; LDS dest = wave-uniform base + lane*16
    __builtin_amdgcn_global_load_lds(
        (const __attribute__((address_space(1))) void*)g,
        (__attribute__((address_space(3))) void*)l, 16, 0, 0);
}

// Clobber-free waits (R3-proven formulation: no "memory" clobber, pinned
// with sched_barrier so the issue-order ledger stays intact).
#define SCHEDB()  __builtin_amdgcn_sched_barrier(0)
#define VM0()     do { SCHEDB(); asm volatile("s_waitcnt vmcnt(0)"); SCHEDB(); } while (0)
#define LGKM0()   do { asm volatile("s_waitcnt lgkmcnt(0)"); SCHEDB(); } while (0)

// DPP row_ror:N within each 16-lane row -- VALU-pipe lane rotate.
#define ROR16(v, N) \
    ((unsigned)__builtin_amdgcn_update_dpp(0, (int)(v), 0x120 + (N), 0xF, 0xF, true))

// ---------------------------------------------------------------------------
// Prep (fused): x -> i8 plane; codes -> i8 plane + c_sq (exact fp32).
// Blocks [0, 8192): x elements. Blocks [8192, 9216): one wave per code row.
// ---------------------------------------------------------------------------
__global__ __launch_bounds__(256) void convert_kernel(const float* __restrict__ x,
                                                      const float* __restrict__ codes,
                                                      unsigned* __restrict__ xq,
                                                      unsigned* __restrict__ cq,
                                                      float* __restrict__ csq) {
    const int XB = (B_SZ * D_SZ) / 4 / 256;   // 8192
    if (blockIdx.x < XB) {
        const int tid = blockIdx.x * 256 + threadIdx.x;
        const float4 v = ((const float4*)x)[tid];
        xq[tid] = q4(v);
    } else {
        const int t = threadIdx.x;
        const int wave = t >> 6;
        const int lane = t & 63;
        const int code = (blockIdx.x - XB) * 4 + wave;
        const float4* cp = (const float4*)(codes + (size_t)code * D_SZ);
        float s = 0.0f;
        #pragma unroll
        for (int u = 0; u < 2; ++u) {
            const float4 v = cp[lane + 64 * u];
            cq[(size_t)code * (D_SZ / 4) + lane + 64 * u] = q4(v);
            s = fmaf(v.x, v.x, s); s = fmaf(v.y, v.y, s);
            s = fmaf(v.z, v.z, s); s = fmaf(v.w, v.w, s);
        }
        #pragma unroll
        for (int off = 32; off; off >>= 1) s += __shfl_down(s, off, 64);
        if (lane == 0) csq[code] = s;
    }
}

// ---------------------------------------------------------------------------
// Main: i8 MFMA GEMM (mfma_i32_16x16x64_i8). R15: the R11 B-resident
// structure at TWO blocks/CU (R11's pre-committed follow-up, never run).
// Block = 512 rows x 128 cols. B panel = 128 x 512 = 64 KB in 4 persistent
// kt slots; A single 16 KB buffer with register staging. LDS = 80 KB ->
// 2 blocks/CU: the sibling block fills the VM0-stall and rendezvous
// bubbles that were fully exposed at R11's 1 block/CU (the mechanism that
// kept R5's naive loop competitive). Wave = 32 rows x 64 cols (wm=wave&3,
// wn=wave>>2; acc[2][4]) so the epilogue keeps the per-(row, 64-col-group)
// table format (hb = bx*2 + wn). Phase skeleton VERBATIM R11:
// ds_read A->regs, lgkm(0), barrier, stage next A (+B on rt0), MFMA from
// regs + B LDS, explicit vmcnt(0), barrier. All row-group bases stay
// multiples of 8 -> same swizzle read constant. K order per accumulator
// identical -> integer-exact -> table bits identical -> EPS unchanged.
// Grid 32x32 = 1024 blocks = 4 rounds of 2 blocks/CU.
// ---------------------------------------------------------------------------
__global__ __launch_bounds__(512, 4) void gemm_argmin_kernel(
        const unsigned char* __restrict__ xq,
        const unsigned char* __restrict__ cq,
        const float* __restrict__ csq,
        uint2* __restrict__ table) {
    __shared__ unsigned char sB[4][128][128];   // 64 KB: persistent B panel
    __shared__ unsigned char sA[128][128];      // 16 KB: single A buffer

    const int t = threadIdx.x;
    const int wave = t >> 6;     // 0..7
    const int lane = t & 63;
    const int quad = lane >> 4;
    const int l15 = lane & 15;
    const int wm = wave & 3;     // 0..3 -> 32-row strip of the 128-row tile
    const int wn = wave >> 2;    // 0..1 -> 64-col half

    const int rowbase0 = blockIdx.y * 512;  // 4 row-tiles of 128
    const int colbase = blockIdx.x * 128;   // code cols

    // staging geometry: one gload16 = 8 rows x 128 B, linear LDS dest,
    // pre-swizzled global source (16B chunk' = chunk ^ (row&7)).
    const int lrow = lane >> 3;                   // 0..7 within 8-row group
    const int lchunk = (lane & 7) ^ lrow;         // swizzled 16B-chunk source
    const unsigned char* gA0 = xq + (size_t)(rowbase0 + wave * 16 + lrow) * D_SZ + lchunk * 16;
    const unsigned char* gB0 = cq + (size_t)(colbase + wave * 16 + lrow) * D_SZ + lchunk * 16;

    // epilogue csq terms, loaded up front (L2-resident)
    float cs2[4];
    #pragma unroll
    for (int j = 0; j < 4; ++j)
        cs2[j] = fmaf(0.5f, csq[colbase + wn * 64 + j * 16 + l15], DBIAS);

#define STAGE_A(rt, kt) do { \
        const unsigned char* _g = gA0 + (size_t)(rt) * 128 * D_SZ + (kt) * 128; \
        gload16(_g,                    &sA[wave * 16][0]); \
        gload16(_g + (size_t)8 * D_SZ, &sA[wave * 16 + 8][0]); \
    } while (0)
#define STAGE_B(kt) do { \
        const unsigned char* _g = gB0 + (kt) * 128; \
        gload16(_g,                    &sB[kt][wave * 16][0]); \
        gload16(_g + (size_t)8 * D_SZ, &sB[kt][wave * 16 + 8][0]); \
    } while (0)
#define LDA_REGS() do { \
        _Pragma("unroll") for (int ks = 0; ks < 2; ++ks) { \
            const int cc = (((ks * 4 + quad) ^ (l15 & 7))) * 16; \
            _Pragma("unroll") for (int i = 0; i < 2; ++i) \
                areg[ks][i] = *(const intx4*)&sA[wm * 32 + i * 16 + l15][cc]; \
        } \
    } while (0)
#define COMPUTE_KT(kt) do { \
        _Pragma("unroll") for (int ks = 0; ks < 2; ++ks) { \
            const int cc = (((ks * 4 + quad) ^ (l15 & 7))) * 16; \
            intx4 b[4]; \
            _Pragma("unroll") for (int j = 0; j < 4; ++j) \
                b[j] = *(const intx4*)&sB[kt][wn * 64 + j * 16 + l15][cc]; \
            _Pragma("unroll") for (int i = 0; i < 2; ++i) \
                _Pragma("unroll") for (int j = 0; j < 4; ++j) \
                    acc[i][j] = __builtin_amdgcn_mfma_i32_16x16x64_i8(areg[ks][i], b[j], acc[i][j], 0, 0, 0); \
        } \
    } while (0)
#define MERGE_STEP(N) do { \
        const unsigned ok1 = ROR16(k1, N); \
        const unsigned ok2 = ROR16(k2, N); \
        const unsigned hi = max(k1, ok1); \
        const unsigned w2 = (k1 < ok1) ? k2 : ok2; \
        k1 = min(k1, ok1); \
        k2 = min(hi, w2); \
    } while (0)

    // prologue: B slot 0 + A(rt=0, kt=0); explicit drain before first read
    STAGE_B(0);
    STAGE_A(0, 0);
    VM0();
    __syncthreads();

    const int hb = blockIdx.x * 2 + wn;   // 64-col group index, 0..63

    for (int rt = 0; rt < 4; ++rt) {      // runtime loop (small body)
        intx4 acc[2][4];
        #pragma unroll
        for (int i = 0; i < 2; ++i)
            #pragma unroll
            for (int j = 0; j < 4; ++j) acc[i][j] = (intx4)0;

        #pragma unroll
        for (int kt = 0; kt < 4; ++kt) {
            intx4 areg[2][2];
            LDA_REGS();                     // [1] A -> regs
            LGKM0();                        // [2] my reads complete
            __syncthreads();                // [3] all waves' reads complete
            if (kt < 3) STAGE_A(rt, kt + 1);          // [4] overwrite is safe
            else if (rt < 3) STAGE_A(rt + 1, 0);
            if (rt == 0 && kt < 3) STAGE_B(kt + 1);
            COMPUTE_KT(kt);                 // [5] MFMA from regs + B LDS
            VM0();                          // [6] stage landed
            __syncthreads();
        }

        // ---- epilogue for this 128-row tile (registers + global only)
        #pragma unroll
        for (int i = 0; i < 2; ++i) {
            #pragma unroll
            for (int r = 0; r < 4; ++r) {
                unsigned k[4];
                #pragma unroll
                for (int j = 0; j < 4; ++j) {
                    const float d = fmaf(-(float)acc[i][j][r], INV_S2, cs2[j]);   // > 0
                    k[j] = (__float_as_uint(d) & 0xFFFFFFC0u) | (unsigned)(j * 16 + l15);
                }
                const unsigned lo1 = min(k[0], k[1]), hi1 = max(k[0], k[1]);
                const unsigned lo2 = min(k[2], k[3]), hi2 = max(k[2], k[3]);
                unsigned k1 = min(lo1, lo2);
                unsigned k2 = min(max(lo1, lo2), min(hi1, hi2));
                MERGE_STEP(8); MERGE_STEP(4); MERGE_STEP(2); MERGE_STEP(1);
                if (l15 == 0) {
                    const int grow = rowbase0 + rt * 128 + wm * 32 + i * 16 + quad * 4 + r;
                    table[(size_t)grow * 64 + hb] = make_uint2(k1, k2);
                }
            }
        }
    }
#undef STAGE_A
#undef STAGE_B
#undef LDA_REGS
#undef COMPUTE_KT
#undef MERGE_STEP
}

// ---------------------------------------------------------------------------
// Re-rank + gather + loss partials -- the R4/R12 tail (fastest measured).
// FOUR rows per wave (batched table loads + x loads, resolve, batched
// gathers). Keys are positive-float bits; col = 64*lane + (key & 63).
// Exact fp32 re-rank within EPS -> indices bit-exact.
// ---------------------------------------------------------------------------
__global__ __launch_bounds__(256) void rerank_gather_loss_kernel(
        const float* __restrict__ x,
        const float* __restrict__ codes,
        const float* __restrict__ csq,
        const uint2* __restrict__ table,
        float* __restrict__ outq,
        float* __restrict__ out_idx_f,
        float* __restrict__ partials) {
    __shared__ float red[4];
    const int t = threadIdx.x;
    const int wave = t >> 6;
    const int lane = t & 63;
    const int row0 = (blockIdx.x * 4 + wave) * 4;   // 4 consecutive rows

    // ---- batched independent loads: 4 table entries + 4 x rows
    uint2 e[4];
    float4 xv[4][2];
    #pragma unroll
    for (int r = 0; r < 4; ++r) {
        e[r] = table[(size_t)(row0 + r) * 64 + lane];
        const float4* xp = (const float4*)(x + (size_t)(row0 + r) * D_SZ);
        xv[r][0] = xp[lane];
        xv[r][1] = xp[lane + 64];
    }

    // ---- resolve argmin per row
    int fin[4];
    #pragma unroll
    for (int r = 0; r < 4; ++r) {
        const unsigned k1 = e[r].x, k2 = e[r].y;
        unsigned mk = k1;
        #pragma unroll
        for (int off = 32; off; off >>= 1)
            mk = min(mk, (unsigned)__shfl_xor((int)mk, off, 64));

        const float thr = __uint_as_float(mk & 0xFFFFFFC0u) + EPS;
        const float v1 = __uint_as_float(k1 & 0xFFFFFFC0u);
        const float v2 = __uint_as_float(k2 & 0xFFFFFFC0u);
        const unsigned long long b1 = __ballot(v1 <= thr);
        const unsigned long long b2 = __ballot(v2 <= thr);

        const unsigned long long bm = __ballot(k1 == mk);
        fin[r] = (__ffsll(bm) - 1) * 64 + (int)(mk & 63u);

        if (__popcll(b1) + __popcll(b2) > 1) {       // exact fp32 re-rank
            const int c1 = lane * 64 + (int)(k1 & 63u);
            const int c2 = lane * 64 + (int)(k2 & 63u);
            float bv = 3.4e38f; int bi = 0x7FFFFFFF;
            #pragma unroll
            for (int pass = 0; pass < 2; ++pass) {
                unsigned long long bb = pass ? b2 : b1;
                const int myc = pass ? c2 : c1;
                while (bb) {
                    const int src = __ffsll((unsigned long long)bb) - 1;
                    bb &= bb - 1;
                    const int ci = __shfl(myc, src, 64);
                    const float4* cp = (const float4*)(codes + (size_t)ci * D_SZ);
                    const float4 c0 = cp[lane];
                    const float4 c1v = cp[lane + 64];
                    float s = 0.0f;
                    s = fmaf(xv[r][0].x, c0.x, s);  s = fmaf(xv[r][0].y, c0.y, s);
                    s = fmaf(xv[r][0].z, c0.z, s);  s = fmaf(xv[r][0].w, c0.w, s);
                    s = fmaf(xv[r][1].x, c1v.x, s); s = fmaf(xv[r][1].y, c1v.y, s);
                    s = fmaf(xv[r][1].z, c1v.z, s); s = fmaf(xv[r][1].w, c1v.w, s);
                    #pragma unroll
                    for (int off = 32; off; off >>= 1) s += __shfl_xor(s, off, 64);
                    const float d = fmaf(0.5f, csq[ci], -s);   // exact fp32
                    if (d < bv || (d == bv && ci < bi)) { bv = d; bi = ci; }
                }
            }
            fin[r] = bi;
        }
    }

    // ---- batched independent gathers
    float4 qv[4][2];
    #pragma unroll
    for (int r = 0; r < 4; ++r) {
        const float4* qp = (const float4*)(codes + (size_t)fin[r] * D_SZ);
        qv[r][0] = qp[lane];
        qv[r][1] = qp[lane + 64];
    }

    // ---- writes + loss partial
    float s = 0.0f;
    #pragma unroll
    for (int r = 0; r < 4; ++r) {
        float4* op = (float4*)(outq + (size_t)(row0 + r) * D_SZ);
        op[lane] = qv[r][0];
        op[lane + 64] = qv[r][1];
        const float d0 = xv[r][0].x - qv[r][0].x, d1 = xv[r][0].y - qv[r][0].y;
        const float d2 = xv[r][0].z - qv[r][0].z, d3 = xv[r][0].w - qv[r][0].w;
        const float d4 = xv[r][1].x - qv[r][1].x, d5 = xv[r][1].y - qv[r][1].y;
        const float d6 = xv[r][1].z - qv[r][1].z, d7 = xv[r][1].w - qv[r][1].w;
        s += d0 * d0 + d1 * d1 + d2 * d2 + d3 * d3 + d4 * d4 + d5 * d5 + d6 * d6 + d7 * d7;
        if (lane == 0) out_idx_f[row0 + r] = (float)fin[r];
    }
    #pragma unroll
    for (int off = 32; off; off >>= 1) s += __shfl_down(s, off, 64);
    if (lane == 0) red[wave] = s;
    __syncthreads();
    if (t == 0) partials[blockIdx.x] = red[0] + red[1] + red[2] + red[3];
}

// ---------------------------------------------------------------------------
// Loss: sum 1024 block partials -> loss_slot. One block.
// ---------------------------------------------------------------------------
__global__ __launch_bounds__(256) void loss_reduce_kernel(const float* __restrict__ partials,
                                                          float* __restrict__ loss_slot) {
    __shared__ float red[4];
    const int t = threadIdx.x;
    const int wave = t >> 6;
    const int lane = t & 63;
    float s = 0.0f;
    #pragma unroll
    for (int i = 0; i < (B_SZ / 16) / 256; ++i) s += partials[i * 256 + t];
    #pragma unroll
    for (int off = 32; off; off >>= 1) s += __shfl_down(s, off, 64);
    if (lane == 0) red[wave] = s;
    __syncthreads();
    if (t == 0)
        *loss_slot = (red[0] + red[1] + red[2] + red[3]) * (1.25f / (float)B_SZ);
}

// ---------------------------------------------------------------------------
extern "C" void kernel_launch(void* const* d_in, const int* in_sizes, int n_in,
                              void* d_out, int out_size, void* d_ws, size_t ws_size,
                              hipStream_t stream) {
    const float* x = (const float*)d_in[0];
    const float* codes = (const float*)d_in[1];  // (1, C, D) contiguous

    float* outq = (float*)d_out;                       // [B*D]
    float* out_idx_f = outq + (size_t)B_SZ * D_SZ;     // [B]
    float* loss_slot = out_idx_f + B_SZ;               // [1]

    // workspace: xq 8M | cq 2M | csq 16K | table 8M (uint2) | partials 4K
    unsigned char* xq = (unsigned char*)d_ws;
    unsigned char* cq = xq + (size_t)B_SZ * D_SZ;
    float* csq = (float*)(cq + (size_t)C_SZ * D_SZ);
    uint2* table = (uint2*)(csq + C_SZ);
    float* partials = (float*)(table + (size_t)B_SZ * 64);

    const int XB = (B_SZ * D_SZ) / 4 / 256;           // 8192
    const int CB = C_SZ / 4;                          // 1024
    convert_kernel<<<XB + CB, 256, 0, stream>>>(x, codes, (unsigned*)xq, (unsigned*)cq, csq);
    gemm_argmin_kernel<<<dim3(C_SZ / 128, B_SZ / 512), 512, 0, stream>>>(xq, cq, csq, table);
    rerank_gather_loss_kernel<<<B_SZ / 16, 256, 0, stream>>>(x, codes, csq, table, outq, out_idx_f, partials);
    loss_reduce_kernel<<<1, 256, 0, stream>>>(partials, loss_slot);
}